// Round 5
// baseline (222.535 us; speedup 1.0000x reference)
//
#include <hip/hip_runtime.h>
#include <math.h>

typedef __bf16 bf16x8 __attribute__((ext_vector_type(8)));
typedef float f32x4 __attribute__((ext_vector_type(4)));
typedef short s16x4 __attribute__((ext_vector_type(4)));

#define GPTR(p) ((const __attribute__((address_space(1))) void*)(p))
#define LPTR(p) ((__attribute__((address_space(3))) void*)(p))

// softmax scale folded into Q: 1/sqrt(64) * log2(e)
#define QSCALE 0.18033688011112042f

__device__ __forceinline__ unsigned short f2bf(float f) {
  unsigned int u = __float_as_uint(f);
  u += 0x7FFFu + ((u >> 16) & 1u);   // RNE; inputs are finite
  return (unsigned short)(u >> 16);
}

// pack two positive floats to bf16x2 (round-half-up) in 3 VALU ops
__device__ __forceinline__ unsigned int pack_bf2(float lo, float hi) {
  return __builtin_amdgcn_perm(__float_as_uint(hi) + 0x8000u,
                               __float_as_uint(lo) + 0x8000u, 0x07060302u);
}

__device__ __forceinline__ float fast_exp2(float x) {
#if __has_builtin(__builtin_amdgcn_exp2f)
  return __builtin_amdgcn_exp2f(x);
#else
  return exp2f(x);
#endif
}

__device__ __forceinline__ f32x4 zero4() {
  f32x4 z; z[0] = 0.f; z[1] = 0.f; z[2] = 0.f; z[3] = 0.f; return z;
}

// ---------- fp32 -> bf16 elementwise ----------
__global__ void conv_x_bf16(const float* __restrict__ in, unsigned short* __restrict__ out) {
  int i = (blockIdx.x * 256 + threadIdx.x) * 4;
  float4 v = *(const float4*)(in + i);
  ushort4 o;
  o.x = f2bf(v.x); o.y = f2bf(v.y); o.z = f2bf(v.z); o.w = f2bf(v.w);
  *(ushort4*)(out + i) = o;
}

// ---------- out[n][k] = bf16(in[k][n]); in is [K][N] fp32 ----------
__global__ void transpose_conv(const float* __restrict__ in, unsigned short* __restrict__ out,
                               int K, int N) {
  __shared__ float tile[64][65];
  int k0 = blockIdx.y * 64, n0 = blockIdx.x * 64;
  int t = threadIdx.x;
#pragma unroll
  for (int p = 0; p < 16; ++p) {
    int l = p * 256 + t; int r = l >> 6, c = l & 63;
    tile[r][c] = in[(size_t)(k0 + r) * N + n0 + c];
  }
  __syncthreads();
#pragma unroll
  for (int p = 0; p < 16; ++p) {
    int l = p * 256 + t; int r = l >> 6, c = l & 63;
    out[(size_t)(n0 + r) * K + k0 + c] = f2bf(tile[c][r]);
  }
}

// ---------- QKV projection: C = A @ Bt^T + bias ----------
// Q -> row-major [bh][2048][64], pre-scaled by QSCALE.
// K -> tiled+swizzled [bh][tile32][64 r][8 chunks], chunk c stored at c^(r&7).
// V -> tiled+swizzled [bh][tile32][64 d][8 chunks over t], chunk c at c^(d&7).
__global__ __launch_bounds__(256) void gemm_qkv(
    const unsigned short* __restrict__ A, const unsigned short* __restrict__ Bt,
    const float* __restrict__ bias,
    unsigned short* __restrict__ Qd, unsigned short* __restrict__ Kd,
    unsigned short* __restrict__ Vtd) {
  __shared__ unsigned short As[128 * 32];
  __shared__ unsigned short Bs[128 * 32];
  const int tid = threadIdx.x, wave = tid >> 6, lane = tid & 63;
  const int quad = lane >> 4, l16 = lane & 15;
  const int wm = (wave >> 1) * 64, wn = (wave & 1) * 64;
  const int m0 = blockIdx.y * 128, n0 = blockIdx.x * 128;
  f32x4 acc[4][4];
#pragma unroll
  for (int i = 0; i < 4; ++i)
#pragma unroll
    for (int j = 0; j < 4; ++j) acc[i][j] = zero4();

  const int c = wave * 64 + lane;
  const int rA = c >> 2, o16 = (c & 3) * 8;

  for (int k0 = 0; k0 < 1024; k0 += 32) {
    __syncthreads();
    __builtin_amdgcn_global_load_lds(GPTR(A + (size_t)(m0 + rA) * 1024 + k0 + o16),
                                     LPTR(As + wave * 512), 16, 0, 0);
    __builtin_amdgcn_global_load_lds(GPTR(A + (size_t)(m0 + 64 + rA) * 1024 + k0 + o16),
                                     LPTR(As + 2048 + wave * 512), 16, 0, 0);
    __builtin_amdgcn_global_load_lds(GPTR(Bt + (size_t)(n0 + rA) * 1024 + k0 + o16),
                                     LPTR(Bs + wave * 512), 16, 0, 0);
    __builtin_amdgcn_global_load_lds(GPTR(Bt + (size_t)(n0 + 64 + rA) * 1024 + k0 + o16),
                                     LPTR(Bs + 2048 + wave * 512), 16, 0, 0);
    __syncthreads();
    bf16x8 af[4], bfr[4];
#pragma unroll
    for (int mt = 0; mt < 4; ++mt)
      af[mt] = *(const bf16x8*)(As + (wm + mt * 16 + l16) * 32 + quad * 8);
#pragma unroll
    for (int nt = 0; nt < 4; ++nt)
      bfr[nt] = *(const bf16x8*)(Bs + (wn + nt * 16 + l16) * 32 + quad * 8);
#pragma unroll
    for (int mt = 0; mt < 4; ++mt)
#pragma unroll
      for (int nt = 0; nt < 4; ++nt)
        acc[mt][nt] = __builtin_amdgcn_mfma_f32_16x16x32_bf16(af[mt], bfr[nt], acc[mt][nt], 0, 0, 0);
  }

  // Epilogue: C layout col=lane&15, row=quad*4+reg. n -> (h, q/k/v, d); m -> (b, t).
#pragma unroll
  for (int mt = 0; mt < 4; ++mt) {
#pragma unroll
    for (int nt = 0; nt < 4; ++nt) {
      int m = m0 + wm + mt * 16 + quad * 4;
      int n = n0 + wn + nt * 16 + l16;
      float bv = bias[n];
      int h = n / 192, rem = n - h * 192;
      int which = rem >> 6, d = rem & 63;
      int b = m >> 11, t0 = m & 2047;
      size_t head = (size_t)(b * 16 + h);
      f32x4 a = acc[mt][nt];
      if (which == 0) {                    // Q row-major, pre-scaled
        size_t base = (head * 2048 + t0) * 64 + d;
#pragma unroll
        for (int i = 0; i < 4; ++i)
          Qd[base + (size_t)i * 64] = f2bf((a[i] + bv) * QSCALE);
      } else if (which == 1) {             // K tiled+swizzled
        size_t base = head * 131072 + (size_t)(t0 >> 6) * 4096;
#pragma unroll
        for (int i = 0; i < 4; ++i) {
          int tt = t0 + i;
          Kd[base + (tt & 63) * 64 + (((d >> 3) ^ (tt & 7)) << 3) + (d & 7)] = f2bf(a[i] + bv);
        }
      } else {                             // V tiled+swizzled (rows = d, cols = t)
        size_t base = head * 131072 + (size_t)(t0 >> 6) * 4096;
        ushort4 o;
        o.x = f2bf(a[0] + bv); o.y = f2bf(a[1] + bv);
        o.z = f2bf(a[2] + bv); o.w = f2bf(a[3] + bv);
        *(ushort4*)(Vtd + base + d * 64 + (((((t0 & 63) >> 3)) ^ (d & 7)) << 3) + (t0 & 7)) = o;
      }
    }
  }
}

// ---------- Flash attention v4: grid (T/128, B*H), 128 q/block ----------
// Wave roles: 2x2 split — qhalf = wave>>1 (64 q), kh2 = wave&1 (32 keys of each
// 64-key tile). S^T = K·Q^T via 16x16x32; P stays in REGISTERS (S^T C-layout ==
// B-layout of 16x16x16 MFMA); O^T partial += V^T·P^T via 16x16x16. No-max
// softmax, l accumulated per-lane across all tiles, one cross-wave reduce at end.
__global__ __launch_bounds__(256) void flash_attn(
    const unsigned short* __restrict__ Qg,   // [bh][2048][64] row-major, scaled
    const unsigned short* __restrict__ Kg,   // [bh][32][4096] swizzled tiles
    const unsigned short* __restrict__ Vg,   // [bh][32][4096] swizzled tiles
    unsigned short* __restrict__ att) {      // [4096][1024] bf16
  __shared__ __align__(16) char smem[33792]; // tiles (16KB) overlaid by reduce buf (32KB+512B)
  unsigned short* Ks = (unsigned short*)smem;          // [64][64] swizzled
  unsigned short* Vs = Ks + 4096;                      // [64 d][64 t] swizzled
  float* redO = (float*)smem;                          // 2 x 4096 floats
  float* redL = (float*)(smem + 32768);                // 128 floats
  const int tid = threadIdx.x, wave = tid >> 6, lane = tid & 63;
  const int quad = lane >> 4, l16 = lane & 15;
  const int h7 = l16 & 7;
  const int qhalf = wave >> 1, kh2 = wave & 1;
  const int bh = blockIdx.y;
  const int q0 = blockIdx.x * 128 + qhalf * 64;

  // Q B-frags: [qg][kh], lane l16 = q-col, k(d) = kh*32 + quad*8 + j
  bf16x8 bq[4][2];
#pragma unroll
  for (int qg = 0; qg < 4; ++qg)
#pragma unroll
    for (int kh = 0; kh < 2; ++kh)
      bq[qg][kh] = *(const bf16x8*)(Qg + ((size_t)bh * 2048 + q0 + qg * 16 + l16) * 64 + kh * 32 + quad * 8);

  f32x4 o[4][4];                             // [mt(d)][qg] partial O^T over this wave's keys
#pragma unroll
  for (int mt = 0; mt < 4; ++mt)
#pragma unroll
    for (int qg = 0; qg < 4; ++qg) o[mt][qg] = zero4();
  float lacc[4] = {0.f, 0.f, 0.f, 0.f};      // per-lane partial sum (keys quad*4+r of kt blocks)

  const unsigned short* Kt = Kg + (size_t)bh * 131072;
  const unsigned short* Vt = Vg + (size_t)bh * 131072;

  for (int tile = 0; tile < 32; ++tile) {
    __syncthreads();                         // prior iter's LDS reads done
    const unsigned short* Kb = Kt + tile * 4096 + lane * 8;   // per-lane 16B
    const unsigned short* Vb = Vt + tile * 4096 + lane * 8;
    __builtin_amdgcn_global_load_lds(GPTR(Kb + wave * 512),       LPTR(Ks + wave * 512), 16, 0, 0);
    __builtin_amdgcn_global_load_lds(GPTR(Kb + (4 + wave) * 512), LPTR(Ks + (4 + wave) * 512), 16, 0, 0);
    __builtin_amdgcn_global_load_lds(GPTR(Vb + wave * 512),       LPTR(Vs + wave * 512), 16, 0, 0);
    __builtin_amdgcn_global_load_lds(GPTR(Vb + (4 + wave) * 512), LPTR(Vs + (4 + wave) * 512), 16, 0, 0);
    __syncthreads();                         // staging complete

    // ---- S^T = K · Q^T : s[qg][kt], key = kh2*32 + kt*16 + quad*4 + r, q = l16
    f32x4 s[4][2];
#pragma unroll
    for (int qg = 0; qg < 4; ++qg)
#pragma unroll
      for (int kt = 0; kt < 2; ++kt) s[qg][kt] = zero4();
#pragma unroll
    for (int kt = 0; kt < 2; ++kt) {
      int krow = kh2 * 32 + kt * 16 + l16;
#pragma unroll
      for (int kh = 0; kh < 2; ++kh) {
        bf16x8 a = *(const bf16x8*)(Ks + krow * 64 + (((kh * 4 + quad) ^ h7) << 3));
#pragma unroll
        for (int qg = 0; qg < 4; ++qg)
          s[qg][kt] = __builtin_amdgcn_mfma_f32_16x16x32_bf16(a, bq[qg][kh], s[qg][kt], 0, 0, 0);
      }
    }

    // ---- softmax (no max) -> P frags in registers; PV via 16x16x16 ----
#pragma unroll
    for (int kt = 0; kt < 2; ++kt) {
      s16x4 pB[4];
#pragma unroll
      for (int qg = 0; qg < 4; ++qg) {
        float p0 = fast_exp2(s[qg][kt][0]);
        float p1 = fast_exp2(s[qg][kt][1]);
        float p2 = fast_exp2(s[qg][kt][2]);
        float p3 = fast_exp2(s[qg][kt][3]);
        lacc[qg] += (p0 + p1) + (p2 + p3);
        union { unsigned int u[2]; s16x4 v; } pk;
        pk.u[0] = pack_bf2(p0, p1);
        pk.u[1] = pack_bf2(p2, p3);
        pB[qg] = pk.v;                       // B-frag: n=q=l16, k=quad*4+j  (== C-layout)
      }
      int cV = kh2 * 4 + kt * 2 + (quad >> 1);  // V chunk for keys kh2*32+kt*16+quad*4..
#pragma unroll
      for (int mt = 0; mt < 4; ++mt) {
        s16x4 aV = *(const s16x4*)(Vs + (mt * 16 + l16) * 64 + ((cV ^ h7) << 3) + (quad & 1) * 4);
#pragma unroll
        for (int qg = 0; qg < 4; ++qg)
          o[mt][qg] = __builtin_amdgcn_mfma_f32_16x16x16bf16_1k(aV, pB[qg], o[mt][qg], 0, 0, 0);
      }
    }
  }

  // ---- final: reduce l over quads, then combine the two key-half waves ----
  float lfull[4];
#pragma unroll
  for (int qg = 0; qg < 4; ++qg) {
    float lw = lacc[qg];
    lw += __shfl_xor(lw, 16);
    lw += __shfl_xor(lw, 32);
    lfull[qg] = lw;                          // full sum over this wave's 32 keys, per q=l16
  }
  __syncthreads();                           // all tile-LDS reads done; safe to overlay
  if (kh2 == 1) {
    float* ob = redO + qhalf * 4096;
#pragma unroll
    for (int mt = 0; mt < 4; ++mt)
#pragma unroll
      for (int qg = 0; qg < 4; ++qg)
        *(f32x4*)(ob + ((qg * 4 + mt) * 4 + quad) * 64 + l16 * 4) = o[mt][qg];
    if (quad == 0) {
#pragma unroll
      for (int qg = 0; qg < 4; ++qg)
        redL[qhalf * 64 + qg * 16 + l16] = lfull[qg];
    }
  }
  __syncthreads();
  if (kh2 == 0) {
    int b = bh >> 4, h = bh & 15;
    float* ob = redO + qhalf * 4096;
#pragma unroll
    for (int qg = 0; qg < 4; ++qg) {
      float linv = 1.f / (lfull[qg] + redL[qhalf * 64 + qg * 16 + l16]);
      unsigned short* orow = att + ((size_t)b * 2048 + q0 + qg * 16 + l16) * 1024 + h * 64;
#pragma unroll
      for (int mt = 0; mt < 4; ++mt) {
        f32x4 part = *(const f32x4*)(ob + ((qg * 4 + mt) * 4 + quad) * 64 + l16 * 4);
        ushort4 ov;
        ov.x = f2bf((o[mt][qg][0] + part[0]) * linv);
        ov.y = f2bf((o[mt][qg][1] + part[1]) * linv);
        ov.z = f2bf((o[mt][qg][2] + part[2]) * linv);
        ov.w = f2bf((o[mt][qg][3] + part[3]) * linv);
        *(ushort4*)(orow + mt * 16 + quad * 4) = ov;
      }
    }
  }
}

// ---------- Output projection: out = att @ Wot^T + bias, fp32 out ----------
__global__ __launch_bounds__(256) void gemm_out(
    const unsigned short* __restrict__ A, const unsigned short* __restrict__ Bt,
    const float* __restrict__ bias, float* __restrict__ out) {
  __shared__ unsigned short As[128 * 32];
  __shared__ unsigned short Bs[128 * 32];
  const int tid = threadIdx.x, wave = tid >> 6, lane = tid & 63;
  const int quad = lane >> 4, l16 = lane & 15;
  const int wm = (wave >> 1) * 64, wn = (wave & 1) * 64;
  const int m0 = blockIdx.y * 128, n0 = blockIdx.x * 128;
  f32x4 acc[4][4];
#pragma unroll
  for (int i = 0; i < 4; ++i)
#pragma unroll
    for (int j = 0; j < 4; ++j) acc[i][j] = zero4();

  const int c = wave * 64 + lane;
  const int rA = c >> 2, o16 = (c & 3) * 8;

  for (int k0 = 0; k0 < 1024; k0 += 32) {
    __syncthreads();
    __builtin_amdgcn_global_load_lds(GPTR(A + (size_t)(m0 + rA) * 1024 + k0 + o16),
                                     LPTR(As + wave * 512), 16, 0, 0);
    __builtin_amdgcn_global_load_lds(GPTR(A + (size_t)(m0 + 64 + rA) * 1024 + k0 + o16),
                                     LPTR(As + 2048 + wave * 512), 16, 0, 0);
    __builtin_amdgcn_global_load_lds(GPTR(Bt + (size_t)(n0 + rA) * 1024 + k0 + o16),
                                     LPTR(Bs + wave * 512), 16, 0, 0);
    __builtin_amdgcn_global_load_lds(GPTR(Bt + (size_t)(n0 + 64 + rA) * 1024 + k0 + o16),
                                     LPTR(Bs + 2048 + wave * 512), 16, 0, 0);
    __syncthreads();
    bf16x8 af[4], bfr[4];
#pragma unroll
    for (int mt = 0; mt < 4; ++mt)
      af[mt] = *(const bf16x8*)(As + (wm + mt * 16 + l16) * 32 + quad * 8);
#pragma unroll
    for (int nt = 0; nt < 4; ++nt)
      bfr[nt] = *(const bf16x8*)(Bs + (wn + nt * 16 + l16) * 32 + quad * 8);
#pragma unroll
    for (int mt = 0; mt < 4; ++mt)
#pragma unroll
      for (int nt = 0; nt < 4; ++nt)
        acc[mt][nt] = __builtin_amdgcn_mfma_f32_16x16x32_bf16(af[mt], bfr[nt], acc[mt][nt], 0, 0, 0);
  }

#pragma unroll
  for (int mt = 0; mt < 4; ++mt) {
#pragma unroll
    for (int nt = 0; nt < 4; ++nt) {
      int m = m0 + wm + mt * 16 + quad * 4;
      int n = n0 + wn + nt * 16 + l16;
      float bv = bias[n];
      float* orow = out + (size_t)m * 1024 + n;
      orow[0]        = acc[mt][nt][0] + bv;
      orow[1024]     = acc[mt][nt][1] + bv;
      orow[2 * 1024] = acc[mt][nt][2] + bv;
      orow[3 * 1024] = acc[mt][nt][3] + bv;
    }
  }
}

extern "C" void kernel_launch(void* const* d_in, const int* in_sizes, int n_in,
                              void* d_out, int out_size, void* d_ws, size_t ws_size,
                              hipStream_t stream) {
  const float* x    = (const float*)d_in[0];   // [2,2048,1024]
  const float* Wqkv = (const float*)d_in[1];   // [1024,3072]
  const float* bqkv = (const float*)d_in[2];   // [3072]
  const float* Wo   = (const float*)d_in[3];   // [1024,1024]
  const float* bo   = (const float*)d_in[4];   // [1024]
  float* out = (float*)d_out;

  // workspace layout (bf16 = unsigned short)
  unsigned short* xb    = (unsigned short*)d_ws;                 // 4096*1024
  unsigned short* wqkvt = xb    + (size_t)4096 * 1024;           // 3072*1024
  unsigned short* wot   = wqkvt + (size_t)3072 * 1024;           // 1024*1024
  unsigned short* Qd    = wot   + (size_t)1024 * 1024;           // [32][2048][64] scaled
  unsigned short* Kd    = Qd    + (size_t)32 * 2048 * 64;        // [32][32][4096] swizzled
  unsigned short* Vtd   = Kd    + (size_t)32 * 2048 * 64;        // [32][32][4096] swizzled
  unsigned short* attb  = Vtd   + (size_t)32 * 2048 * 64;        // 4096*1024

  conv_x_bf16<<<4096, 256, 0, stream>>>(x, xb);
  transpose_conv<<<dim3(48, 16), 256, 0, stream>>>(Wqkv, wqkvt, 1024, 3072);
  transpose_conv<<<dim3(16, 16), 256, 0, stream>>>(Wo, wot, 1024, 1024);
  gemm_qkv<<<dim3(24, 32), 256, 0, stream>>>(xb, wqkvt, bqkv, Qd, Kd, Vtd);
  flash_attn<<<dim3(16, 32), 256, 0, stream>>>(Qd, Kd, Vtd, attb);
  gemm_out<<<dim3(8, 32), 256, 0, stream>>>(attb, wot, bo, out);
}

// Round 6
// 219.944 us; speedup vs baseline: 1.0118x; 1.0118x over previous
//
#include <hip/hip_runtime.h>
#include <math.h>

typedef __bf16 bf16x8 __attribute__((ext_vector_type(8)));
typedef float f32x4 __attribute__((ext_vector_type(4)));
typedef short s16x4 __attribute__((ext_vector_type(4)));

#define GPTR(p) ((const __attribute__((address_space(1))) void*)(p))
#define LPTR(p) ((__attribute__((address_space(3))) void*)(p))

// softmax scale folded into Q: 1/sqrt(64) * log2(e)
#define QSCALE 0.18033688011112042f

__device__ __forceinline__ unsigned short f2bf(float f) {
  unsigned int u = __float_as_uint(f);
  u += 0x7FFFu + ((u >> 16) & 1u);   // RNE; inputs are finite
  return (unsigned short)(u >> 16);
}

// pack two positive floats to bf16x2 (round-half-up) in 3 VALU ops
__device__ __forceinline__ unsigned int pack_bf2(float lo, float hi) {
  return __builtin_amdgcn_perm(__float_as_uint(hi) + 0x8000u,
                               __float_as_uint(lo) + 0x8000u, 0x07060302u);
}

__device__ __forceinline__ float fast_exp2(float x) {
#if __has_builtin(__builtin_amdgcn_exp2f)
  return __builtin_amdgcn_exp2f(x);
#else
  return exp2f(x);
#endif
}

__device__ __forceinline__ f32x4 zero4() {
  f32x4 z; z[0] = 0.f; z[1] = 0.f; z[2] = 0.f; z[3] = 0.f; return z;
}

// ---------- fp32 -> bf16 elementwise ----------
__global__ void conv_x_bf16(const float* __restrict__ in, unsigned short* __restrict__ out) {
  int i = (blockIdx.x * 256 + threadIdx.x) * 4;
  float4 v = *(const float4*)(in + i);
  ushort4 o;
  o.x = f2bf(v.x); o.y = f2bf(v.y); o.z = f2bf(v.z); o.w = f2bf(v.w);
  *(ushort4*)(out + i) = o;
}

// ---------- out[n][k] = bf16(in[k][n]); in is [K][N] fp32 ----------
__global__ void transpose_conv(const float* __restrict__ in, unsigned short* __restrict__ out,
                               int K, int N) {
  __shared__ float tile[64][65];
  int k0 = blockIdx.y * 64, n0 = blockIdx.x * 64;
  int t = threadIdx.x;
#pragma unroll
  for (int p = 0; p < 16; ++p) {
    int l = p * 256 + t; int r = l >> 6, c = l & 63;
    tile[r][c] = in[(size_t)(k0 + r) * N + n0 + c];
  }
  __syncthreads();
#pragma unroll
  for (int p = 0; p < 16; ++p) {
    int l = p * 256 + t; int r = l >> 6, c = l & 63;
    out[(size_t)(n0 + r) * K + k0 + c] = f2bf(tile[c][r]);
  }
}

// ---------- QKV projection: C = A @ Bt^T + bias ----------
// Q -> row-major [bh][2048][64], pre-scaled by QSCALE.
// K -> tiled+swizzled [bh][tile32][64 r][8 chunks], chunk c stored at c^(r&7).
// V -> tiled+swizzled [bh][tile32][64 d][8 chunks over t], chunk c at c^(d&7).
__global__ __launch_bounds__(256) void gemm_qkv(
    const unsigned short* __restrict__ A, const unsigned short* __restrict__ Bt,
    const float* __restrict__ bias,
    unsigned short* __restrict__ Qd, unsigned short* __restrict__ Kd,
    unsigned short* __restrict__ Vtd) {
  __shared__ unsigned short As[128 * 32];
  __shared__ unsigned short Bs[128 * 32];
  const int tid = threadIdx.x, wave = tid >> 6, lane = tid & 63;
  const int quad = lane >> 4, l16 = lane & 15;
  const int wm = (wave >> 1) * 64, wn = (wave & 1) * 64;
  const int m0 = blockIdx.y * 128, n0 = blockIdx.x * 128;
  f32x4 acc[4][4];
#pragma unroll
  for (int i = 0; i < 4; ++i)
#pragma unroll
    for (int j = 0; j < 4; ++j) acc[i][j] = zero4();

  const int c = wave * 64 + lane;
  const int rA = c >> 2, o16 = (c & 3) * 8;

  for (int k0 = 0; k0 < 1024; k0 += 32) {
    __syncthreads();
    __builtin_amdgcn_global_load_lds(GPTR(A + (size_t)(m0 + rA) * 1024 + k0 + o16),
                                     LPTR(As + wave * 512), 16, 0, 0);
    __builtin_amdgcn_global_load_lds(GPTR(A + (size_t)(m0 + 64 + rA) * 1024 + k0 + o16),
                                     LPTR(As + 2048 + wave * 512), 16, 0, 0);
    __builtin_amdgcn_global_load_lds(GPTR(Bt + (size_t)(n0 + rA) * 1024 + k0 + o16),
                                     LPTR(Bs + wave * 512), 16, 0, 0);
    __builtin_amdgcn_global_load_lds(GPTR(Bt + (size_t)(n0 + 64 + rA) * 1024 + k0 + o16),
                                     LPTR(Bs + 2048 + wave * 512), 16, 0, 0);
    __syncthreads();
    bf16x8 af[4], bfr[4];
#pragma unroll
    for (int mt = 0; mt < 4; ++mt)
      af[mt] = *(const bf16x8*)(As + (wm + mt * 16 + l16) * 32 + quad * 8);
#pragma unroll
    for (int nt = 0; nt < 4; ++nt)
      bfr[nt] = *(const bf16x8*)(Bs + (wn + nt * 16 + l16) * 32 + quad * 8);
#pragma unroll
    for (int mt = 0; mt < 4; ++mt)
#pragma unroll
      for (int nt = 0; nt < 4; ++nt)
        acc[mt][nt] = __builtin_amdgcn_mfma_f32_16x16x32_bf16(af[mt], bfr[nt], acc[mt][nt], 0, 0, 0);
  }

  // Epilogue: C layout col=lane&15, row=quad*4+reg. n -> (h, q/k/v, d); m -> (b, t).
#pragma unroll
  for (int mt = 0; mt < 4; ++mt) {
#pragma unroll
    for (int nt = 0; nt < 4; ++nt) {
      int m = m0 + wm + mt * 16 + quad * 4;
      int n = n0 + wn + nt * 16 + l16;
      float bv = bias[n];
      int h = n / 192, rem = n - h * 192;
      int which = rem >> 6, d = rem & 63;
      int b = m >> 11, t0 = m & 2047;
      size_t head = (size_t)(b * 16 + h);
      f32x4 a = acc[mt][nt];
      if (which == 0) {                    // Q row-major, pre-scaled
        size_t base = (head * 2048 + t0) * 64 + d;
#pragma unroll
        for (int i = 0; i < 4; ++i)
          Qd[base + (size_t)i * 64] = f2bf((a[i] + bv) * QSCALE);
      } else if (which == 1) {             // K tiled+swizzled
        size_t base = head * 131072 + (size_t)(t0 >> 6) * 4096;
#pragma unroll
        for (int i = 0; i < 4; ++i) {
          int tt = t0 + i;
          Kd[base + (tt & 63) * 64 + (((d >> 3) ^ (tt & 7)) << 3) + (d & 7)] = f2bf(a[i] + bv);
        }
      } else {                             // V tiled+swizzled (rows = d, cols = t)
        size_t base = head * 131072 + (size_t)(t0 >> 6) * 4096;
        ushort4 o;
        o.x = f2bf(a[0] + bv); o.y = f2bf(a[1] + bv);
        o.z = f2bf(a[2] + bv); o.w = f2bf(a[3] + bv);
        *(ushort4*)(Vtd + base + d * 64 + (((((t0 & 63) >> 3)) ^ (d & 7)) << 3) + (t0 & 7)) = o;
      }
    }
  }
}

// ---------- Flash attention v5: v4 wave-split + double-buffered staging ----------
// grid (T/128, B*H), 128 q/block. Waves: qhalf = wave>>1, kh2 = wave&1.
// One barrier per tile; stage tile t+1 into alt buffer right after the barrier,
// so the vmcnt drain at the NEXT barrier finds the loads already landed.
__global__ __launch_bounds__(256) void flash_attn(
    const unsigned short* __restrict__ Qg,   // [bh][2048][64] row-major, scaled
    const unsigned short* __restrict__ Kg,   // [bh][32][4096] swizzled tiles
    const unsigned short* __restrict__ Vg,   // [bh][32][4096] swizzled tiles
    unsigned short* __restrict__ att) {      // [4096][1024] bf16
  __shared__ __align__(16) char smem[33792]; // 2x(K+V) tiles 32KB, overlaid by reduce 33.25KB
  unsigned short* Tb = (unsigned short*)smem;          // buf b at Tb + b*8192: K 4096, V 4096
  float* redO = (float*)smem;                          // 2 x 4096 floats
  float* redL = (float*)(smem + 32768);                // 128 floats
  const int tid = threadIdx.x, wave = tid >> 6, lane = tid & 63;
  const int quad = lane >> 4, l16 = lane & 15;
  const int h7 = l16 & 7;
  const int qhalf = wave >> 1, kh2 = wave & 1;
  const int bh = blockIdx.y;
  const int q0 = blockIdx.x * 128 + qhalf * 64;

  // Q B-frags: [qg][kh], lane l16 = q-col, k(d) = kh*32 + quad*8 + j
  bf16x8 bq[4][2];
#pragma unroll
  for (int qg = 0; qg < 4; ++qg)
#pragma unroll
    for (int kh = 0; kh < 2; ++kh)
      bq[qg][kh] = *(const bf16x8*)(Qg + ((size_t)bh * 2048 + q0 + qg * 16 + l16) * 64 + kh * 32 + quad * 8);

  f32x4 o[4][4];                             // [mt(d)][qg] partial O^T over this wave's keys
#pragma unroll
  for (int mt = 0; mt < 4; ++mt)
#pragma unroll
    for (int qg = 0; qg < 4; ++qg) o[mt][qg] = zero4();
  float lacc[4] = {0.f, 0.f, 0.f, 0.f};

  const unsigned short* Kt = Kg + (size_t)bh * 131072 + lane * 8;  // per-lane 16B
  const unsigned short* Vt = Vg + (size_t)bh * 131072 + lane * 8;

  // prologue: stage tile 0 into buf 0
  {
    unsigned short* Kb = Tb;               // buf0: K at 0, V at 4096
    __builtin_amdgcn_global_load_lds(GPTR(Kt + wave * 512),          LPTR(Kb + wave * 512), 16, 0, 0);
    __builtin_amdgcn_global_load_lds(GPTR(Kt + (4 + wave) * 512),    LPTR(Kb + (4 + wave) * 512), 16, 0, 0);
    __builtin_amdgcn_global_load_lds(GPTR(Vt + wave * 512),          LPTR(Kb + 4096 + wave * 512), 16, 0, 0);
    __builtin_amdgcn_global_load_lds(GPTR(Vt + (4 + wave) * 512),    LPTR(Kb + 4096 + (4 + wave) * 512), 16, 0, 0);
  }

  for (int tile = 0; tile < 32; ++tile) {
    __syncthreads();                       // stage(tile) landed; buf[(tile+1)&1] reads (iter-1) done
    if (tile + 1 < 32) {                   // prefetch tile+1 into alternate buffer
      unsigned short* Kb = Tb + ((tile + 1) & 1) * 8192;
      const unsigned short* Kg1 = Kt + (tile + 1) * 4096;
      const unsigned short* Vg1 = Vt + (tile + 1) * 4096;
      __builtin_amdgcn_global_load_lds(GPTR(Kg1 + wave * 512),       LPTR(Kb + wave * 512), 16, 0, 0);
      __builtin_amdgcn_global_load_lds(GPTR(Kg1 + (4 + wave) * 512), LPTR(Kb + (4 + wave) * 512), 16, 0, 0);
      __builtin_amdgcn_global_load_lds(GPTR(Vg1 + wave * 512),       LPTR(Kb + 4096 + wave * 512), 16, 0, 0);
      __builtin_amdgcn_global_load_lds(GPTR(Vg1 + (4 + wave) * 512), LPTR(Kb + 4096 + (4 + wave) * 512), 16, 0, 0);
    }
    const unsigned short* Ks = Tb + (tile & 1) * 8192;
    const unsigned short* Vs = Ks + 4096;

    // ---- S^T = K · Q^T : s[qg][kt], key = kh2*32 + kt*16 + quad*4 + r, q = l16
    f32x4 s[4][2];
#pragma unroll
    for (int qg = 0; qg < 4; ++qg)
#pragma unroll
      for (int kt = 0; kt < 2; ++kt) s[qg][kt] = zero4();
#pragma unroll
    for (int kt = 0; kt < 2; ++kt) {
      int krow = kh2 * 32 + kt * 16 + l16;
#pragma unroll
      for (int kh = 0; kh < 2; ++kh) {
        bf16x8 a = *(const bf16x8*)(Ks + krow * 64 + (((kh * 4 + quad) ^ h7) << 3));
#pragma unroll
        for (int qg = 0; qg < 4; ++qg)
          s[qg][kt] = __builtin_amdgcn_mfma_f32_16x16x32_bf16(a, bq[qg][kh], s[qg][kt], 0, 0, 0);
      }
    }

    // ---- softmax (no max) -> P frags in registers; PV via 16x16x16 ----
#pragma unroll
    for (int kt = 0; kt < 2; ++kt) {
      s16x4 pB[4];
#pragma unroll
      for (int qg = 0; qg < 4; ++qg) {
        float p0 = fast_exp2(s[qg][kt][0]);
        float p1 = fast_exp2(s[qg][kt][1]);
        float p2 = fast_exp2(s[qg][kt][2]);
        float p3 = fast_exp2(s[qg][kt][3]);
        lacc[qg] += (p0 + p1) + (p2 + p3);
        union { unsigned int u[2]; s16x4 v; } pk;
        pk.u[0] = pack_bf2(p0, p1);
        pk.u[1] = pack_bf2(p2, p3);
        pB[qg] = pk.v;                     // B-frag: n=q=l16, k=quad*4+j  (== C-layout)
      }
      int cV = kh2 * 4 + kt * 2 + (quad >> 1);
#pragma unroll
      for (int mt = 0; mt < 4; ++mt) {
        s16x4 aV = *(const s16x4*)(Vs + (mt * 16 + l16) * 64 + ((cV ^ h7) << 3) + (quad & 1) * 4);
#pragma unroll
        for (int qg = 0; qg < 4; ++qg)
          o[mt][qg] = __builtin_amdgcn_mfma_f32_16x16x16bf16_1k(aV, pB[qg], o[mt][qg], 0, 0, 0);
      }
    }
  }

  // ---- final: reduce l over quads, then combine the two key-half waves ----
  float lfull[4];
#pragma unroll
  for (int qg = 0; qg < 4; ++qg) {
    float lw = lacc[qg];
    lw += __shfl_xor(lw, 16);
    lw += __shfl_xor(lw, 32);
    lfull[qg] = lw;
  }
  __syncthreads();                         // all tile-LDS reads done; safe to overlay
  if (kh2 == 1) {
    float* ob = redO + qhalf * 4096;
#pragma unroll
    for (int mt = 0; mt < 4; ++mt)
#pragma unroll
      for (int qg = 0; qg < 4; ++qg)
        *(f32x4*)(ob + ((qg * 4 + mt) * 4 + quad) * 64 + l16 * 4) = o[mt][qg];
    if (quad == 0) {
#pragma unroll
      for (int qg = 0; qg < 4; ++qg)
        redL[qhalf * 64 + qg * 16 + l16] = lfull[qg];
    }
  }
  __syncthreads();
  if (kh2 == 0) {
    int b = bh >> 4, h = bh & 15;
    float* ob = redO + qhalf * 4096;
#pragma unroll
    for (int qg = 0; qg < 4; ++qg) {
      float linv = 1.f / (lfull[qg] + redL[qhalf * 64 + qg * 16 + l16]);
      unsigned short* orow = att + ((size_t)b * 2048 + q0 + qg * 16 + l16) * 1024 + h * 64;
#pragma unroll
      for (int mt = 0; mt < 4; ++mt) {
        f32x4 part = *(const f32x4*)(ob + ((qg * 4 + mt) * 4 + quad) * 64 + l16 * 4);
        ushort4 ov;
        ov.x = f2bf((o[mt][qg][0] + part[0]) * linv);
        ov.y = f2bf((o[mt][qg][1] + part[1]) * linv);
        ov.z = f2bf((o[mt][qg][2] + part[2]) * linv);
        ov.w = f2bf((o[mt][qg][3] + part[3]) * linv);
        *(ushort4*)(orow + mt * 16 + quad * 4) = ov;
      }
    }
  }
}

// ---------- Output projection: out = att @ Wot^T + bias, fp32 out ----------
__global__ __launch_bounds__(256) void gemm_out(
    const unsigned short* __restrict__ A, const unsigned short* __restrict__ Bt,
    const float* __restrict__ bias, float* __restrict__ out) {
  __shared__ unsigned short As[128 * 32];
  __shared__ unsigned short Bs[128 * 32];
  const int tid = threadIdx.x, wave = tid >> 6, lane = tid & 63;
  const int quad = lane >> 4, l16 = lane & 15;
  const int wm = (wave >> 1) * 64, wn = (wave & 1) * 64;
  const int m0 = blockIdx.y * 128, n0 = blockIdx.x * 128;
  f32x4 acc[4][4];
#pragma unroll
  for (int i = 0; i < 4; ++i)
#pragma unroll
    for (int j = 0; j < 4; ++j) acc[i][j] = zero4();

  const int c = wave * 64 + lane;
  const int rA = c >> 2, o16 = (c & 3) * 8;

  for (int k0 = 0; k0 < 1024; k0 += 32) {
    __syncthreads();
    __builtin_amdgcn_global_load_lds(GPTR(A + (size_t)(m0 + rA) * 1024 + k0 + o16),
                                     LPTR(As + wave * 512), 16, 0, 0);
    __builtin_amdgcn_global_load_lds(GPTR(A + (size_t)(m0 + 64 + rA) * 1024 + k0 + o16),
                                     LPTR(As + 2048 + wave * 512), 16, 0, 0);
    __builtin_amdgcn_global_load_lds(GPTR(Bt + (size_t)(n0 + rA) * 1024 + k0 + o16),
                                     LPTR(Bs + wave * 512), 16, 0, 0);
    __builtin_amdgcn_global_load_lds(GPTR(Bt + (size_t)(n0 + 64 + rA) * 1024 + k0 + o16),
                                     LPTR(Bs + 2048 + wave * 512), 16, 0, 0);
    __syncthreads();
    bf16x8 af[4], bfr[4];
#pragma unroll
    for (int mt = 0; mt < 4; ++mt)
      af[mt] = *(const bf16x8*)(As + (wm + mt * 16 + l16) * 32 + quad * 8);
#pragma unroll
    for (int nt = 0; nt < 4; ++nt)
      bfr[nt] = *(const bf16x8*)(Bs + (wn + nt * 16 + l16) * 32 + quad * 8);
#pragma unroll
    for (int mt = 0; mt < 4; ++mt)
#pragma unroll
      for (int nt = 0; nt < 4; ++nt)
        acc[mt][nt] = __builtin_amdgcn_mfma_f32_16x16x32_bf16(af[mt], bfr[nt], acc[mt][nt], 0, 0, 0);
  }

#pragma unroll
  for (int mt = 0; mt < 4; ++mt) {
#pragma unroll
    for (int nt = 0; nt < 4; ++nt) {
      int m = m0 + wm + mt * 16 + quad * 4;
      int n = n0 + wn + nt * 16 + l16;
      float bv = bias[n];
      float* orow = out + (size_t)m * 1024 + n;
      orow[0]        = acc[mt][nt][0] + bv;
      orow[1024]     = acc[mt][nt][1] + bv;
      orow[2 * 1024] = acc[mt][nt][2] + bv;
      orow[3 * 1024] = acc[mt][nt][3] + bv;
    }
  }
}

extern "C" void kernel_launch(void* const* d_in, const int* in_sizes, int n_in,
                              void* d_out, int out_size, void* d_ws, size_t ws_size,
                              hipStream_t stream) {
  const float* x    = (const float*)d_in[0];   // [2,2048,1024]
  const float* Wqkv = (const float*)d_in[1];   // [1024,3072]
  const float* bqkv = (const float*)d_in[2];   // [3072]
  const float* Wo   = (const float*)d_in[3];   // [1024,1024]
  const float* bo   = (const float*)d_in[4];   // [1024]
  float* out = (float*)d_out;

  // workspace layout (bf16 = unsigned short)
  unsigned short* xb    = (unsigned short*)d_ws;                 // 4096*1024
  unsigned short* wqkvt = xb    + (size_t)4096 * 1024;           // 3072*1024
  unsigned short* wot   = wqkvt + (size_t)3072 * 1024;           // 1024*1024
  unsigned short* Qd    = wot   + (size_t)1024 * 1024;           // [32][2048][64] scaled
  unsigned short* Kd    = Qd    + (size_t)32 * 2048 * 64;        // [32][32][4096] swizzled
  unsigned short* Vtd   = Kd    + (size_t)32 * 2048 * 64;        // [32][32][4096] swizzled
  unsigned short* attb  = Vtd   + (size_t)32 * 2048 * 64;        // 4096*1024

  conv_x_bf16<<<4096, 256, 0, stream>>>(x, xb);
  transpose_conv<<<dim3(48, 16), 256, 0, stream>>>(Wqkv, wqkvt, 1024, 3072);
  transpose_conv<<<dim3(16, 16), 256, 0, stream>>>(Wo, wot, 1024, 1024);
  gemm_qkv<<<dim3(24, 32), 256, 0, stream>>>(xb, wqkvt, bqkv, Qd, Kd, Vtd);
  flash_attn<<<dim3(16, 32), 256, 0, stream>>>(Qd, Kd, Vtd, attb);
  gemm_out<<<dim3(8, 32), 256, 0, stream>>>(attb, wot, bo, out);
}